// Round 1
// baseline (276.288 us; speedup 1.0000x reference)
//
#include <hip/hip_runtime.h>

constexpr int Hh = 2048;
constexpr int Ww = 2048;
constexpr int NN = Hh * Ww;
constexpr int W4 = Ww / 4;             // row stride in float4
constexpr int NN4 = NN / 4;            // plane stride in float4
constexpr int RAD = 10;                // size=21 -> radius 10
constexpr float EPSf = 1e-9f;
constexpr float MASK_THRf = 0.001f;
constexpr int BH = 16;                 // band height for vertical prefix
constexpr int NB = Hh / BH;            // 128 bands
constexpr int TOTW = NB * Ww;          // floats per totals/offsets array
constexpr int NSLOT = 32;              // atomic spreading slots
constexpr int SEGW = 58;               // output float4 cols per wave (64 - 2*3 halo)
constexpr int NSEG = 9;                // ceil(W4 / SEGW) = ceil(512/58)
constexpr int HBLOCKS = Hh * NSEG / 4; // 4608 blocks, 4 waves each

__device__ inline float rcpf(float x) { return __builtin_amdgcn_rcpf(x); }

__device__ inline float waveReduce(float v) {
    #pragma unroll
    for (int o = 32; o > 0; o >>= 1) v += __shfl_down(v, o, 64);
    return v;
}

__device__ inline float4 f4zero() { float4 z; z.x = z.y = z.z = z.w = 0.f; return z; }
__device__ inline float4 f4add(float4 a, float4 b) {
    float4 r; r.x = a.x + b.x; r.y = a.y + b.y; r.z = a.z + b.z; r.w = a.w + b.w; return r;
}
__device__ inline float4 f4sub(float4 a, float4 b) {
    float4 r; r.x = a.x - b.x; r.y = a.y - b.y; r.z = a.z - b.z; r.w = a.w - b.w; return r;
}
__device__ inline void add4(float4& a, const float4 b) { a.x += b.x; a.y += b.y; a.z += b.z; a.w += b.w; }

// Direct 21-tap horizontal box of v (zero-padded outside the wave's halo) via
// neighbor-lane shuffles. Lane c holds v(4c..4c+3). All shuffles independent:
//   box(4c+1) = S[c-2]+S[c-1]+S[c]+S[c+1]+S[c+2] + v3@(c-3)
//   box(4c+2) = T5 + v0@(c+3)
//   box(4c+0) = box(4c+1) + v2@(c-3) - v3@(c+2)
//   box(4c+3) = box(4c+2) + v1@(c+3) - v0@(c-2)
// Valid only for lanes 3..60 (callers discard the halo lanes).
__device__ inline float4 hbox(float4 v, int lane) {
    float S = v.x + v.y + v.z + v.w;
    float Sm2 = __shfl(S, lane - 2, 64);
    float Sm1 = __shfl(S, lane - 1, 64);
    float Sp1 = __shfl(S, lane + 1, 64);
    float Sp2 = __shfl(S, lane + 2, 64);
    float T5 = Sm2 + Sm1 + S + Sp1 + Sp2;
    float wm3 = __shfl(v.w, lane - 3, 64);
    float zm3 = __shfl(v.z, lane - 3, 64);
    float xm2 = __shfl(v.x, lane - 2, 64);
    float wp2 = __shfl(v.w, lane + 2, 64);
    float xp3 = __shfl(v.x, lane + 3, 64);
    float yp3 = __shfl(v.y, lane + 3, 64);
    float4 r;
    r.y = T5 + wm3;
    r.z = T5 + xp3;
    r.x = r.y + zm3 - wp2;
    r.w = r.z + yp3 - xm2;
    return r;
}

// ---------------- K1p: band-local vertical prefix of (mask, b, b2) ----------------
__global__ __launch_bounds__(256) void k1p(
        const float* __restrict__ I, const float* __restrict__ B,
        float* __restrict__ vpm, float* __restrict__ vpb, float* __restrict__ vpb2,
        float* __restrict__ tm, float* __restrict__ tb, float* __restrict__ tb2) {
    int x4 = blockIdx.x * 256 + threadIdx.x;     // float4 column
    int y0 = blockIdx.y * BH;
    const float4* I4 = (const float4*)I;
    const float4* B4 = (const float4*)B;
    float4 am = f4zero(), ab = f4zero(), ab2 = f4zero();
    #pragma unroll
    for (int r = 0; r < BH; ++r) {
        int idx = (y0 + r) * W4 + x4;
        float4 iv = I4[idx], bv = B4[idx];
        am.x += (iv.x > MASK_THRf) ? 1.f : 0.f;
        am.y += (iv.y > MASK_THRf) ? 1.f : 0.f;
        am.z += (iv.z > MASK_THRf) ? 1.f : 0.f;
        am.w += (iv.w > MASK_THRf) ? 1.f : 0.f;
        ab.x += bv.x; ab.y += bv.y; ab.z += bv.z; ab.w += bv.w;
        ab2.x += bv.x * bv.x; ab2.y += bv.y * bv.y;
        ab2.z += bv.z * bv.z; ab2.w += bv.w * bv.w;
        ((float4*)vpm)[idx] = am;
        ((float4*)vpb)[idx] = ab;
        ((float4*)vpb2)[idx] = ab2;
    }
    int t = blockIdx.y * W4 + x4;
    ((float4*)tm)[t] = am; ((float4*)tb)[t] = ab; ((float4*)tb2)[t] = ab2;
}

// ---------------- koff: exclusive prefix over band totals (per stream, per column) ----------------
__global__ __launch_bounds__(256) void koff(
        const float* __restrict__ t0, const float* __restrict__ t1, const float* __restrict__ t2,
        float* __restrict__ o0, float* __restrict__ o1, float* __restrict__ o2) {
    int col = blockIdx.x * 256 + threadIdx.x;    // float4 column
    const float4* t; float4* o;
    if (blockIdx.y == 0)      { t = (const float4*)t0; o = (float4*)o0; }
    else if (blockIdx.y == 1) { t = (const float4*)t1; o = (float4*)o1; }
    else                      { t = (const float4*)t2; o = (float4*)o2; }
    float4 acc = f4zero();
    #pragma unroll 8
    for (int b = 0; b < NB; ++b) {
        o[b * W4 + col] = acc;
        float4 v = t[b * W4 + col];
        add4(acc, v);
    }
}

// ---------------- K2s: segment-parallel h-box of v-boxed (m,b,b2) + phase-A reductions ----------------
__device__ inline void k2_pix(float bm, float bb, float bb2, float Iv, float ev,
                              float u0, float u1, float u2, float u3, float* a) {
    float rn = rcpf(bm + EPSf);
    float bK = bb * rn;
    float b2K = bb2 * rn;
    float p0 = u0 * u0, p1 = u1 * u1, p2 = u2 * u2, p3 = u3 * u3;
    a[0] += Iv * p0;
    a[1] += p0;
    float A = (Iv - ev) * bK;
    a[2] += A * p1; a[3] += A * p2; a[4] += A * p3;
    a[5] += b2K * p1; a[6] += b2K * p2; a[7] += b2K * p3;
}

__global__ __launch_bounds__(256) void k2s(
        const float* __restrict__ vpm, const float* __restrict__ vpb, const float* __restrict__ vpb2,
        const float* __restrict__ om, const float* __restrict__ ob, const float* __restrict__ ob2,
        const float* __restrict__ I, const float* __restrict__ E, const float* __restrict__ U,
        float* __restrict__ accA) {
    int lane = threadIdx.x & 63;
    int wid = blockIdx.x * 4 + (threadIdx.x >> 6);
    int row = wid / NSEG;
    int seg = wid - row * NSEG;
    int xc = seg * SEGW - 3 + lane;              // float4 column this lane loads
    bool inb = (unsigned)xc < (unsigned)W4;
    int xl = inb ? xc : 0;

    int yup = row + RAD; if (yup > Hh - 1) yup = Hh - 1;
    int ydn = row - RAD - 1;
    bool hasDn = ydn >= 0;
    int upBase = yup * W4 + xl;
    int dnBase = (hasDn ? ydn * W4 : 0) + xl;
    int obUp = (yup / BH) * W4 + xl;
    int obDn = (hasDn ? (ydn / BH) * W4 : 0) + xl;

    const float4* Pm = (const float4*)vpm;
    const float4* Pb = (const float4*)vpb;
    const float4* Pq = (const float4*)vpb2;
    const float4* Om = (const float4*)om;
    const float4* Ob = (const float4*)ob;
    const float4* Oq = (const float4*)ob2;

    float4 vm = f4zero(), vb = f4zero(), vq = f4zero();
    if (inb) {
        vm = f4add(Pm[upBase], Om[obUp]);
        vb = f4add(Pb[upBase], Ob[obUp]);
        vq = f4add(Pq[upBase], Oq[obUp]);
        if (hasDn) {
            vm = f4sub(vm, f4add(Pm[dnBase], Om[obDn]));
            vb = f4sub(vb, f4add(Pb[dnBase], Ob[obDn]));
            vq = f4sub(vq, f4add(Pq[dnBase], Oq[obDn]));
        }
    }

    float4 bm = hbox(vm, lane);
    float4 bb = hbox(vb, lane);
    float4 bq = hbox(vq, lane);

    float a[8] = {0, 0, 0, 0, 0, 0, 0, 0};
    if (inb && lane >= 3 && lane <= 60) {
        const float4* I4 = (const float4*)I;
        const float4* E4 = (const float4*)E;
        const float4* U0 = (const float4*)U;
        const float4* U1 = U0 + NN4;
        const float4* U2 = U1 + NN4;
        const float4* U3 = U2 + NN4;
        int xo = row * W4 + xc;
        float4 Iv = I4[xo], Ev = E4[xo];
        float4 u0 = U0[xo], u1 = U1[xo], u2 = U2[xo], u3 = U3[xo];
        k2_pix(bm.x, bb.x, bq.x, Iv.x, Ev.x, u0.x, u1.x, u2.x, u3.x, a);
        k2_pix(bm.y, bb.y, bq.y, Iv.y, Ev.y, u0.y, u1.y, u2.y, u3.y, a);
        k2_pix(bm.z, bb.z, bq.z, Iv.z, Ev.z, u0.z, u1.z, u2.z, u3.z, a);
        k2_pix(bm.w, bb.w, bq.w, Iv.w, Ev.w, u0.w, u1.w, u2.w, u3.w, a);
    }

    __shared__ float sred[4][8];
    int wave = threadIdx.x >> 6;
    #pragma unroll
    for (int k = 0; k < 8; ++k) a[k] = waveReduce(a[k]);
    if (lane == 0) {
        #pragma unroll
        for (int k = 0; k < 8; ++k) sred[wave][k] = a[k];
    }
    __syncthreads();
    if (threadIdx.x < 8) {
        float s = sred[0][threadIdx.x] + sred[1][threadIdx.x] +
                  sred[2][threadIdx.x] + sred[3][threadIdx.x];
        atomicAdd(&accA[threadIdx.x * NSLOT + (blockIdx.x & (NSLOT - 1))], s);
    }
}

// ---------------- K3: fold slots, compute v ----------------
__global__ void k3_v(const float* __restrict__ accA, float* __restrict__ vV) {
    int lane = threadIdx.x;
    float s[8];
    #pragma unroll
    for (int k = 0; k < 8; ++k) {
        float v = (lane < NSLOT) ? accA[k * NSLOT + lane] : 0.f;
        s[k] = waveReduce(v);
    }
    if (lane == 0) {
        vV[0] = s[0] / (s[1] + EPSf);
        vV[1] = s[2] / (s[5] + EPSf);
        vV[2] = s[3] / (s[6] + EPSf);
        vV[3] = s[4] / (s[7] + EPSf);
    }
}

// ---------------- K4p: band-local vertical prefix of (P, Q) ----------------
__global__ __launch_bounds__(256) void k4p(
        const float* __restrict__ I, const float* __restrict__ E, const float* __restrict__ U,
        const float* __restrict__ vV,
        float* __restrict__ vpP, float* __restrict__ vpQ,
        float* __restrict__ tP, float* __restrict__ tQ) {
    int x4 = blockIdx.x * 256 + threadIdx.x;
    int y0 = blockIdx.y * BH;
    float v0 = vV[0], v1 = vV[1], v2 = vV[2], v3 = vV[3];
    float w0 = v0 * v0, w1 = v1 * v1, w2 = v2 * v2, w3 = v3 * v3;
    const float4* I4 = (const float4*)I;
    const float4* E4 = (const float4*)E;
    const float4* U0 = (const float4*)U;
    const float4* U1 = U0 + NN4;
    const float4* U2 = U1 + NN4;
    const float4* U3 = U2 + NN4;
    float4 aP = f4zero(), aQ = f4zero();
    #pragma unroll
    for (int r = 0; r < BH; ++r) {
        int idx = (y0 + r) * W4 + x4;
        float4 Iv = I4[idx], Ev = E4[idx];
        float4 a0 = U0[idx], a1 = U1[idx], a2 = U2[idx], a3 = U3[idx];
        float p0, p1, p2, p3;
        p0 = a0.x * a0.x; p1 = a1.x * a1.x; p2 = a2.x * a2.x; p3 = a3.x * a3.x;
        aP.x += (Iv.x - Ev.x) * (v0 * p0 + v1 * p1 + v2 * p2 + v3 * p3);
        aQ.x += w0 * p0 + w1 * p1 + w2 * p2 + w3 * p3;
        p0 = a0.y * a0.y; p1 = a1.y * a1.y; p2 = a2.y * a2.y; p3 = a3.y * a3.y;
        aP.y += (Iv.y - Ev.y) * (v0 * p0 + v1 * p1 + v2 * p2 + v3 * p3);
        aQ.y += w0 * p0 + w1 * p1 + w2 * p2 + w3 * p3;
        p0 = a0.z * a0.z; p1 = a1.z * a1.z; p2 = a2.z * a2.z; p3 = a3.z * a3.z;
        aP.z += (Iv.z - Ev.z) * (v0 * p0 + v1 * p1 + v2 * p2 + v3 * p3);
        aQ.z += w0 * p0 + w1 * p1 + w2 * p2 + w3 * p3;
        p0 = a0.w * a0.w; p1 = a1.w * a1.w; p2 = a2.w * a2.w; p3 = a3.w * a3.w;
        aP.w += (Iv.w - Ev.w) * (v0 * p0 + v1 * p1 + v2 * p2 + v3 * p3);
        aQ.w += w0 * p0 + w1 * p1 + w2 * p2 + w3 * p3;
        ((float4*)vpP)[idx] = aP;
        ((float4*)vpQ)[idx] = aQ;
    }
    int t = blockIdx.y * W4 + x4;
    ((float4*)tP)[t] = aP; ((float4*)tQ)[t] = aQ;
}

// ---------------- K5s: segment-parallel h-box of v-boxed (P,Q,m) + masked combine + loss ----------------
__global__ __launch_bounds__(256) void k5s(
        const float* __restrict__ vpP, const float* __restrict__ vpQ, const float* __restrict__ vpm,
        const float* __restrict__ oP, const float* __restrict__ oQ, const float* __restrict__ om,
        const float* __restrict__ I, const float* __restrict__ B,
        float* __restrict__ accL) {
    int lane = threadIdx.x & 63;
    int wid = blockIdx.x * 4 + (threadIdx.x >> 6);
    int row = wid / NSEG;
    int seg = wid - row * NSEG;
    int xc = seg * SEGW - 3 + lane;
    bool inb = (unsigned)xc < (unsigned)W4;
    int xl = inb ? xc : 0;

    int yup = row + RAD; if (yup > Hh - 1) yup = Hh - 1;
    int ydn = row - RAD - 1;
    bool hasDn = ydn >= 0;
    int upBase = yup * W4 + xl;
    int dnBase = (hasDn ? ydn * W4 : 0) + xl;
    int obUp = (yup / BH) * W4 + xl;
    int obDn = (hasDn ? (ydn / BH) * W4 : 0) + xl;

    const float4* Pp4 = (const float4*)vpP;
    const float4* Pq4 = (const float4*)vpQ;
    const float4* Pm4 = (const float4*)vpm;
    const float4* Op4 = (const float4*)oP;
    const float4* Oq4 = (const float4*)oQ;
    const float4* Om4 = (const float4*)om;

    float4 vP = f4zero(), vQ = f4zero(), vM = f4zero();
    if (inb) {
        vP = f4add(Pp4[upBase], Op4[obUp]);
        vQ = f4add(Pq4[upBase], Oq4[obUp]);
        vM = f4add(Pm4[upBase], Om4[obUp]);
        if (hasDn) {
            vP = f4sub(vP, f4add(Pp4[dnBase], Op4[obDn]));
            vQ = f4sub(vQ, f4add(Pq4[dnBase], Oq4[obDn]));
            vM = f4sub(vM, f4add(Pm4[dnBase], Om4[obDn]));
        }
    }

    float4 bP = hbox(vP, lane);
    float4 bQ = hbox(vQ, lane);
    float4 bM = hbox(vM, lane);

    float a = 0.f;
    if (inb && lane >= 3 && lane <= 60) {
        const float4* I4 = (const float4*)I;
        const float4* B4 = (const float4*)B;
        int xo = row * W4 + xc;
        float4 Iv = I4[xo], Bv = B4[xo];
        {
            float rn = rcpf(bM.x + EPSf);
            float bd = bP.x * rn, db = bQ.x * rn;
            float m = (Iv.x > MASK_THRf) ? 1.f : 0.f;
            bd = bd * m + (1.f - m); db = db * m + (1.f - m);
            float d = Bv.x - bd * rcpf(db + EPSf); a += d * d;
        }
        {
            float rn = rcpf(bM.y + EPSf);
            float bd = bP.y * rn, db = bQ.y * rn;
            float m = (Iv.y > MASK_THRf) ? 1.f : 0.f;
            bd = bd * m + (1.f - m); db = db * m + (1.f - m);
            float d = Bv.y - bd * rcpf(db + EPSf); a += d * d;
        }
        {
            float rn = rcpf(bM.z + EPSf);
            float bd = bP.z * rn, db = bQ.z * rn;
            float m = (Iv.z > MASK_THRf) ? 1.f : 0.f;
            bd = bd * m + (1.f - m); db = db * m + (1.f - m);
            float d = Bv.z - bd * rcpf(db + EPSf); a += d * d;
        }
        {
            float rn = rcpf(bM.w + EPSf);
            float bd = bP.w * rn, db = bQ.w * rn;
            float m = (Iv.w > MASK_THRf) ? 1.f : 0.f;
            bd = bd * m + (1.f - m); db = db * m + (1.f - m);
            float d = Bv.w - bd * rcpf(db + EPSf); a += d * d;
        }
    }

    a = waveReduce(a);
    __shared__ float sred[4];
    int wave = threadIdx.x >> 6;
    if (lane == 0) sred[wave] = a;
    __syncthreads();
    if (threadIdx.x == 0) {
        atomicAdd(&accL[blockIdx.x & (NSLOT - 1)], sred[0] + sred[1] + sred[2] + sred[3]);
    }
}

// ---------------- K6: fold slots, write mean ----------------
__global__ void k6_out(const float* __restrict__ accL, float* __restrict__ out) {
    int lane = threadIdx.x;
    float v = (lane < NSLOT) ? accL[lane] : 0.f;
    v = waveReduce(v);
    if (lane == 0) out[0] = v / (float)NN;
}

extern "C" void kernel_launch(void* const* d_in, const int* in_sizes, int n_in,
                              void* d_out, int out_size, void* d_ws, size_t ws_size,
                              hipStream_t stream) {
    const float* I = (const float*)d_in[0];
    const float* U = (const float*)d_in[1];
    const float* B = (const float*)d_in[2];
    const float* E = (const float*)d_in[3];
    // p=2, size=21 fixed by setup_inputs; hard-coded.

    float* vpm  = (float*)d_ws;         // vertical prefix of mask   [NN]
    float* vpb  = vpm + NN;             // prefix of b   -> later prefix of P
    float* vpb2 = vpb + NN;             // prefix of b2  -> later prefix of Q
    float* tm   = vpb2 + NN;            // band totals (mask)   [NB*Ww]
    float* tb   = tm + TOTW;
    float* tb2  = tb + TOTW;
    float* om   = tb2 + TOTW;           // band offsets (mask) — preserved for k5s
    float* ob   = om + TOTW;            // offsets (b)  -> later offsets (P)
    float* ob2  = ob + TOTW;            // offsets (b2) -> later offsets (Q)
    float* accA = ob2 + TOTW;           // 8*NSLOT
    float* accL = accA + 8 * NSLOT;     // NSLOT
    float* vV   = accL + NSLOT;         // v0..v3

    hipMemsetAsync(accA, 0, (8 * NSLOT + NSLOT) * sizeof(float), stream);

    dim3 blk(256);
    dim3 gband(2, NB);                  // 256 blocks for band-prefix kernels

    k1p<<<gband, blk, 0, stream>>>(I, B, vpm, vpb, vpb2, tm, tb, tb2);
    koff<<<dim3(2, 3), blk, 0, stream>>>(tm, tb, tb2, om, ob, ob2);
    k2s<<<HBLOCKS, blk, 0, stream>>>(vpm, vpb, vpb2, om, ob, ob2, I, E, U, accA);
    k3_v<<<1, 64, 0, stream>>>(accA, vV);
    k4p<<<gband, blk, 0, stream>>>(I, E, U, vV, vpb, vpb2, tm, tb);  // P->vpb slot, Q->vpb2 slot
    koff<<<dim3(2, 2), blk, 0, stream>>>(tm, tb, tb2, ob, ob2, om);  // offsets P->ob, Q->ob2 (om untouched)
    k5s<<<HBLOCKS, blk, 0, stream>>>(vpb, vpb2, vpm, ob, ob2, om, I, B, accL);
    k6_out<<<1, 64, 0, stream>>>(accL, (float*)d_out);
}

// Round 2
// 232.448 us; speedup vs baseline: 1.1886x; 1.1886x over previous
//
#include <hip/hip_runtime.h>

constexpr int Hh = 2048;
constexpr int Ww = 2048;
constexpr int NN = Hh * Ww;
constexpr int W4 = Ww / 4;             // row stride in float4
constexpr int NN4 = NN / 4;            // plane stride in float4
constexpr int RAD = 10;                // size=21 -> radius 10
constexpr float EPSf = 1e-9f;
constexpr float MASK_THRf = 0.001f;
constexpr int BH = 16;                 // band height for vertical prefix
constexpr int NB = Hh / BH;            // 128 bands
constexpr int TOTW = NB * Ww;          // floats per totals/offsets array
constexpr int SEGW = 58;               // output float4 cols per wave (64 - 2*3 halo)
constexpr int NSEG = 9;                // ceil(W4 / SEGW) = ceil(512/58)
constexpr int HBLOCKS = Hh * NSEG / 4; // 4608 blocks, 4 waves each

__device__ inline float rcpf(float x) { return __builtin_amdgcn_rcpf(x); }

__device__ inline float waveReduce(float v) {
    #pragma unroll
    for (int o = 32; o > 0; o >>= 1) v += __shfl_down(v, o, 64);
    return v;
}

__device__ inline float4 f4zero() { float4 z; z.x = z.y = z.z = z.w = 0.f; return z; }
__device__ inline float4 f4add(float4 a, float4 b) {
    float4 r; r.x = a.x + b.x; r.y = a.y + b.y; r.z = a.z + b.z; r.w = a.w + b.w; return r;
}
__device__ inline float4 f4sub(float4 a, float4 b) {
    float4 r; r.x = a.x - b.x; r.y = a.y - b.y; r.z = a.z - b.z; r.w = a.w - b.w; return r;
}
__device__ inline void add4(float4& a, const float4 b) { a.x += b.x; a.y += b.y; a.z += b.z; a.w += b.w; }

// Direct 21-tap horizontal box of v (zero-padded outside the wave's halo) via
// neighbor-lane shuffles. Lane c holds v(4c..4c+3). All shuffles independent.
// Valid only for lanes 3..60 (callers discard the halo lanes).
__device__ inline float4 hbox(float4 v, int lane) {
    float S = v.x + v.y + v.z + v.w;
    float Sm2 = __shfl(S, lane - 2, 64);
    float Sm1 = __shfl(S, lane - 1, 64);
    float Sp1 = __shfl(S, lane + 1, 64);
    float Sp2 = __shfl(S, lane + 2, 64);
    float T5 = Sm2 + Sm1 + S + Sp1 + Sp2;
    float wm3 = __shfl(v.w, lane - 3, 64);
    float zm3 = __shfl(v.z, lane - 3, 64);
    float xm2 = __shfl(v.x, lane - 2, 64);
    float wp2 = __shfl(v.w, lane + 2, 64);
    float xp3 = __shfl(v.x, lane + 3, 64);
    float yp3 = __shfl(v.y, lane + 3, 64);
    float4 r;
    r.y = T5 + wm3;
    r.z = T5 + xp3;
    r.x = r.y + zm3 - wp2;
    r.w = r.z + yp3 - xm2;
    return r;
}

// ---------------- K1p: band-local vertical prefix of (mask, b, b2) ----------------
__global__ __launch_bounds__(256) void k1p(
        const float* __restrict__ I, const float* __restrict__ B,
        float* __restrict__ vpm, float* __restrict__ vpb, float* __restrict__ vpb2,
        float* __restrict__ tm, float* __restrict__ tb, float* __restrict__ tb2) {
    int x4 = blockIdx.x * 256 + threadIdx.x;     // float4 column
    int y0 = blockIdx.y * BH;
    const float4* I4 = (const float4*)I;
    const float4* B4 = (const float4*)B;
    float4 am = f4zero(), ab = f4zero(), ab2 = f4zero();
    #pragma unroll
    for (int r = 0; r < BH; ++r) {
        int idx = (y0 + r) * W4 + x4;
        float4 iv = I4[idx], bv = B4[idx];
        am.x += (iv.x > MASK_THRf) ? 1.f : 0.f;
        am.y += (iv.y > MASK_THRf) ? 1.f : 0.f;
        am.z += (iv.z > MASK_THRf) ? 1.f : 0.f;
        am.w += (iv.w > MASK_THRf) ? 1.f : 0.f;
        ab.x += bv.x; ab.y += bv.y; ab.z += bv.z; ab.w += bv.w;
        ab2.x += bv.x * bv.x; ab2.y += bv.y * bv.y;
        ab2.z += bv.z * bv.z; ab2.w += bv.w * bv.w;
        ((float4*)vpm)[idx] = am;
        ((float4*)vpb)[idx] = ab;
        ((float4*)vpb2)[idx] = ab2;
    }
    int t = blockIdx.y * W4 + x4;
    ((float4*)tm)[t] = am; ((float4*)tb)[t] = ab; ((float4*)tb2)[t] = ab2;
}

// ---------------- koff: exclusive prefix over band totals (per stream, per column) ----------------
__global__ __launch_bounds__(256) void koff(
        const float* __restrict__ t0, const float* __restrict__ t1, const float* __restrict__ t2,
        float* __restrict__ o0, float* __restrict__ o1, float* __restrict__ o2) {
    int col = blockIdx.x * 256 + threadIdx.x;    // float4 column
    const float4* t; float4* o;
    if (blockIdx.y == 0)      { t = (const float4*)t0; o = (float4*)o0; }
    else if (blockIdx.y == 1) { t = (const float4*)t1; o = (float4*)o1; }
    else                      { t = (const float4*)t2; o = (float4*)o2; }
    float4 acc = f4zero();
    #pragma unroll 8
    for (int b = 0; b < NB; ++b) {
        o[b * W4 + col] = acc;
        float4 v = t[b * W4 + col];
        add4(acc, v);
    }
}

// ---------------- K2s: segment-parallel h-box of v-boxed (m,b,b2) + phase-A reductions ----------------
__device__ inline void k2_pix(float bm, float bb, float bb2, float Iv, float ev,
                              float u0, float u1, float u2, float u3, float* a) {
    float rn = rcpf(bm + EPSf);
    float bK = bb * rn;
    float b2K = bb2 * rn;
    float p0 = u0 * u0, p1 = u1 * u1, p2 = u2 * u2, p3 = u3 * u3;
    a[0] += Iv * p0;
    a[1] += p0;
    float A = (Iv - ev) * bK;
    a[2] += A * p1; a[3] += A * p2; a[4] += A * p3;
    a[5] += b2K * p1; a[6] += b2K * p2; a[7] += b2K * p3;
}

__global__ __launch_bounds__(256) void k2s(
        const float* __restrict__ vpm, const float* __restrict__ vpb, const float* __restrict__ vpb2,
        const float* __restrict__ om, const float* __restrict__ ob, const float* __restrict__ ob2,
        const float* __restrict__ I, const float* __restrict__ E, const float* __restrict__ U,
        float* __restrict__ partA) {
    int lane = threadIdx.x & 63;
    int wid = blockIdx.x * 4 + (threadIdx.x >> 6);
    int row = wid / NSEG;
    int seg = wid - row * NSEG;
    int xc = seg * SEGW - 3 + lane;              // float4 column this lane loads
    bool inb = (unsigned)xc < (unsigned)W4;
    int xl = inb ? xc : 0;

    int yup = row + RAD; if (yup > Hh - 1) yup = Hh - 1;
    int ydn = row - RAD - 1;
    bool hasDn = ydn >= 0;
    int upBase = yup * W4 + xl;
    int dnBase = (hasDn ? ydn * W4 : 0) + xl;
    int obUp = (yup / BH) * W4 + xl;
    int obDn = (hasDn ? (ydn / BH) * W4 : 0) + xl;

    const float4* Pm = (const float4*)vpm;
    const float4* Pb = (const float4*)vpb;
    const float4* Pq = (const float4*)vpb2;
    const float4* Om = (const float4*)om;
    const float4* Ob = (const float4*)ob;
    const float4* Oq = (const float4*)ob2;

    float4 vm = f4zero(), vb = f4zero(), vq = f4zero();
    if (inb) {
        vm = f4add(Pm[upBase], Om[obUp]);
        vb = f4add(Pb[upBase], Ob[obUp]);
        vq = f4add(Pq[upBase], Oq[obUp]);
        if (hasDn) {
            vm = f4sub(vm, f4add(Pm[dnBase], Om[obDn]));
            vb = f4sub(vb, f4add(Pb[dnBase], Ob[obDn]));
            vq = f4sub(vq, f4add(Pq[dnBase], Oq[obDn]));
        }
    }

    float4 bm = hbox(vm, lane);
    float4 bb = hbox(vb, lane);
    float4 bq = hbox(vq, lane);

    float a[8] = {0, 0, 0, 0, 0, 0, 0, 0};
    if (inb && lane >= 3 && lane <= 60) {
        const float4* I4 = (const float4*)I;
        const float4* E4 = (const float4*)E;
        const float4* U0 = (const float4*)U;
        const float4* U1 = U0 + NN4;
        const float4* U2 = U1 + NN4;
        const float4* U3 = U2 + NN4;
        int xo = row * W4 + xc;
        float4 Iv = I4[xo], Ev = E4[xo];
        float4 u0 = U0[xo], u1 = U1[xo], u2 = U2[xo], u3 = U3[xo];
        k2_pix(bm.x, bb.x, bq.x, Iv.x, Ev.x, u0.x, u1.x, u2.x, u3.x, a);
        k2_pix(bm.y, bb.y, bq.y, Iv.y, Ev.y, u0.y, u1.y, u2.y, u3.y, a);
        k2_pix(bm.z, bb.z, bq.z, Iv.z, Ev.z, u0.z, u1.z, u2.z, u3.z, a);
        k2_pix(bm.w, bb.w, bq.w, Iv.w, Ev.w, u0.w, u1.w, u2.w, u3.w, a);
    }

    __shared__ float sred[4][8];
    int wave = threadIdx.x >> 6;
    #pragma unroll
    for (int k = 0; k < 8; ++k) a[k] = waveReduce(a[k]);
    if (lane == 0) {
        #pragma unroll
        for (int k = 0; k < 8; ++k) sred[wave][k] = a[k];
    }
    __syncthreads();
    // Plain coalesced per-block partial store — NO device-scope atomics
    // (4608 same-line atomics serialized ~40us at the coherence point in R0).
    if (threadIdx.x < 8) {
        float s = sred[0][threadIdx.x] + sred[1][threadIdx.x] +
                  sred[2][threadIdx.x] + sred[3][threadIdx.x];
        partA[(blockIdx.x << 3) + threadIdx.x] = s;
    }
}

// ---------------- K3: reduce per-block partials (HBLOCKS x 8), compute v ----------------
__global__ __launch_bounds__(1024) void k3_v(const float* __restrict__ partA, float* __restrict__ vV) {
    __shared__ float s[1024];
    int tid = threadIdx.x;
    float acc = 0.f;
    // partA has HBLOCKS*8 = 36864 floats = 36 * 1024; perfectly coalesced strided sum.
    #pragma unroll
    for (int j = 0; j < (HBLOCKS * 8) / 1024; ++j) acc += partA[tid + j * 1024];
    s[tid] = acc;
    __syncthreads();
    // reduce over the 128 groups (stride in floats: 512 down to 8), keeping k = tid&7 lanes separate
    #pragma unroll
    for (int st = 512; st >= 8; st >>= 1) {
        if (tid < st) s[tid] += s[tid + st];
        __syncthreads();
    }
    if (tid == 0) {
        vV[0] = s[0] / (s[1] + EPSf);
        vV[1] = s[2] / (s[5] + EPSf);
        vV[2] = s[3] / (s[6] + EPSf);
        vV[3] = s[4] / (s[7] + EPSf);
    }
}

// ---------------- K4p: band-local vertical prefix of (P, Q) ----------------
__global__ __launch_bounds__(256) void k4p(
        const float* __restrict__ I, const float* __restrict__ E, const float* __restrict__ U,
        const float* __restrict__ vV,
        float* __restrict__ vpP, float* __restrict__ vpQ,
        float* __restrict__ tP, float* __restrict__ tQ) {
    int x4 = blockIdx.x * 256 + threadIdx.x;
    int y0 = blockIdx.y * BH;
    float v0 = vV[0], v1 = vV[1], v2 = vV[2], v3 = vV[3];
    float w0 = v0 * v0, w1 = v1 * v1, w2 = v2 * v2, w3 = v3 * v3;
    const float4* I4 = (const float4*)I;
    const float4* E4 = (const float4*)E;
    const float4* U0 = (const float4*)U;
    const float4* U1 = U0 + NN4;
    const float4* U2 = U1 + NN4;
    const float4* U3 = U2 + NN4;
    float4 aP = f4zero(), aQ = f4zero();
    #pragma unroll
    for (int r = 0; r < BH; ++r) {
        int idx = (y0 + r) * W4 + x4;
        float4 Iv = I4[idx], Ev = E4[idx];
        float4 a0 = U0[idx], a1 = U1[idx], a2 = U2[idx], a3 = U3[idx];
        float p0, p1, p2, p3;
        p0 = a0.x * a0.x; p1 = a1.x * a1.x; p2 = a2.x * a2.x; p3 = a3.x * a3.x;
        aP.x += (Iv.x - Ev.x) * (v0 * p0 + v1 * p1 + v2 * p2 + v3 * p3);
        aQ.x += w0 * p0 + w1 * p1 + w2 * p2 + w3 * p3;
        p0 = a0.y * a0.y; p1 = a1.y * a1.y; p2 = a2.y * a2.y; p3 = a3.y * a3.y;
        aP.y += (Iv.y - Ev.y) * (v0 * p0 + v1 * p1 + v2 * p2 + v3 * p3);
        aQ.y += w0 * p0 + w1 * p1 + w2 * p2 + w3 * p3;
        p0 = a0.z * a0.z; p1 = a1.z * a1.z; p2 = a2.z * a2.z; p3 = a3.z * a3.z;
        aP.z += (Iv.z - Ev.z) * (v0 * p0 + v1 * p1 + v2 * p2 + v3 * p3);
        aQ.z += w0 * p0 + w1 * p1 + w2 * p2 + w3 * p3;
        p0 = a0.w * a0.w; p1 = a1.w * a1.w; p2 = a2.w * a2.w; p3 = a3.w * a3.w;
        aP.w += (Iv.w - Ev.w) * (v0 * p0 + v1 * p1 + v2 * p2 + v3 * p3);
        aQ.w += w0 * p0 + w1 * p1 + w2 * p2 + w3 * p3;
        ((float4*)vpP)[idx] = aP;
        ((float4*)vpQ)[idx] = aQ;
    }
    int t = blockIdx.y * W4 + x4;
    ((float4*)tP)[t] = aP; ((float4*)tQ)[t] = aQ;
}

// ---------------- K5s: segment-parallel h-box of v-boxed (P,Q,m) + masked combine + loss ----------------
__global__ __launch_bounds__(256) void k5s(
        const float* __restrict__ vpP, const float* __restrict__ vpQ, const float* __restrict__ vpm,
        const float* __restrict__ oP, const float* __restrict__ oQ, const float* __restrict__ om,
        const float* __restrict__ I, const float* __restrict__ B,
        float* __restrict__ partL) {
    int lane = threadIdx.x & 63;
    int wid = blockIdx.x * 4 + (threadIdx.x >> 6);
    int row = wid / NSEG;
    int seg = wid - row * NSEG;
    int xc = seg * SEGW - 3 + lane;
    bool inb = (unsigned)xc < (unsigned)W4;
    int xl = inb ? xc : 0;

    int yup = row + RAD; if (yup > Hh - 1) yup = Hh - 1;
    int ydn = row - RAD - 1;
    bool hasDn = ydn >= 0;
    int upBase = yup * W4 + xl;
    int dnBase = (hasDn ? ydn * W4 : 0) + xl;
    int obUp = (yup / BH) * W4 + xl;
    int obDn = (hasDn ? (ydn / BH) * W4 : 0) + xl;

    const float4* Pp4 = (const float4*)vpP;
    const float4* Pq4 = (const float4*)vpQ;
    const float4* Pm4 = (const float4*)vpm;
    const float4* Op4 = (const float4*)oP;
    const float4* Oq4 = (const float4*)oQ;
    const float4* Om4 = (const float4*)om;

    float4 vP = f4zero(), vQ = f4zero(), vM = f4zero();
    if (inb) {
        vP = f4add(Pp4[upBase], Op4[obUp]);
        vQ = f4add(Pq4[upBase], Oq4[obUp]);
        vM = f4add(Pm4[upBase], Om4[obUp]);
        if (hasDn) {
            vP = f4sub(vP, f4add(Pp4[dnBase], Op4[obDn]));
            vQ = f4sub(vQ, f4add(Pq4[dnBase], Oq4[obDn]));
            vM = f4sub(vM, f4add(Pm4[dnBase], Om4[obDn]));
        }
    }

    float4 bP = hbox(vP, lane);
    float4 bQ = hbox(vQ, lane);
    float4 bM = hbox(vM, lane);

    float a = 0.f;
    if (inb && lane >= 3 && lane <= 60) {
        const float4* I4 = (const float4*)I;
        const float4* B4 = (const float4*)B;
        int xo = row * W4 + xc;
        float4 Iv = I4[xo], Bv = B4[xo];
        {
            float rn = rcpf(bM.x + EPSf);
            float bd = bP.x * rn, db = bQ.x * rn;
            float m = (Iv.x > MASK_THRf) ? 1.f : 0.f;
            bd = bd * m + (1.f - m); db = db * m + (1.f - m);
            float d = Bv.x - bd * rcpf(db + EPSf); a += d * d;
        }
        {
            float rn = rcpf(bM.y + EPSf);
            float bd = bP.y * rn, db = bQ.y * rn;
            float m = (Iv.y > MASK_THRf) ? 1.f : 0.f;
            bd = bd * m + (1.f - m); db = db * m + (1.f - m);
            float d = Bv.y - bd * rcpf(db + EPSf); a += d * d;
        }
        {
            float rn = rcpf(bM.z + EPSf);
            float bd = bP.z * rn, db = bQ.z * rn;
            float m = (Iv.z > MASK_THRf) ? 1.f : 0.f;
            bd = bd * m + (1.f - m); db = db * m + (1.f - m);
            float d = Bv.z - bd * rcpf(db + EPSf); a += d * d;
        }
        {
            float rn = rcpf(bM.w + EPSf);
            float bd = bP.w * rn, db = bQ.w * rn;
            float m = (Iv.w > MASK_THRf) ? 1.f : 0.f;
            bd = bd * m + (1.f - m); db = db * m + (1.f - m);
            float d = Bv.w - bd * rcpf(db + EPSf); a += d * d;
        }
    }

    a = waveReduce(a);
    __shared__ float sred[4];
    int wave = threadIdx.x >> 6;
    if (lane == 0) sred[wave] = a;
    __syncthreads();
    if (threadIdx.x == 0) {
        partL[blockIdx.x] = sred[0] + sred[1] + sred[2] + sred[3];
    }
}

// ---------------- K6: reduce per-block loss partials, write mean ----------------
__global__ __launch_bounds__(1024) void k6_out(const float* __restrict__ partL, float* __restrict__ out) {
    __shared__ float s[1024];
    int tid = threadIdx.x;
    float acc = 0.f;
    for (int c = tid; c < HBLOCKS; c += 1024) acc += partL[c];
    s[tid] = acc;
    __syncthreads();
    #pragma unroll
    for (int st = 512; st >= 1; st >>= 1) {
        if (tid < st) s[tid] += s[tid + st];
        __syncthreads();
    }
    if (tid == 0) out[0] = s[0] / (float)NN;
}

extern "C" void kernel_launch(void* const* d_in, const int* in_sizes, int n_in,
                              void* d_out, int out_size, void* d_ws, size_t ws_size,
                              hipStream_t stream) {
    const float* I = (const float*)d_in[0];
    const float* U = (const float*)d_in[1];
    const float* B = (const float*)d_in[2];
    const float* E = (const float*)d_in[3];
    // p=2, size=21 fixed by setup_inputs; hard-coded.

    float* vpm  = (float*)d_ws;         // vertical prefix of mask   [NN]
    float* vpb  = vpm + NN;             // prefix of b   -> later prefix of P
    float* vpb2 = vpb + NN;             // prefix of b2  -> later prefix of Q
    float* tm   = vpb2 + NN;            // band totals (mask)   [NB*Ww]
    float* tb   = tm + TOTW;
    float* tb2  = tb + TOTW;
    float* om   = tb2 + TOTW;           // band offsets (mask) — preserved for k5s
    float* ob   = om + TOTW;            // offsets (b)  -> later offsets (P)
    float* ob2  = ob + TOTW;            // offsets (b2) -> later offsets (Q)
    float* vV   = ob2 + TOTW;           // v0..v3

    // Dead-region reuse (no extra workspace):
    //  - tm is consumed by koff#1 before k2s and rewritten by k4p after k3_v
    //    -> k2s per-block partials (HBLOCKS*8 = 36864 floats <= TOTW) live in tm.
    //  - tb2 is dead after koff#1 (koff#2 only uses tm,tb)
    //    -> k5s per-block partials (HBLOCKS floats) live in tb2.
    float* partA = tm;
    float* partL = tb2;

    dim3 blk(256);
    dim3 gband(2, NB);                  // 256 blocks for band-prefix kernels

    k1p<<<gband, blk, 0, stream>>>(I, B, vpm, vpb, vpb2, tm, tb, tb2);
    koff<<<dim3(2, 3), blk, 0, stream>>>(tm, tb, tb2, om, ob, ob2);
    k2s<<<HBLOCKS, blk, 0, stream>>>(vpm, vpb, vpb2, om, ob, ob2, I, E, U, partA);
    k3_v<<<1, 1024, 0, stream>>>(partA, vV);
    k4p<<<gband, blk, 0, stream>>>(I, E, U, vV, vpb, vpb2, tm, tb);  // P->vpb slot, Q->vpb2 slot
    koff<<<dim3(2, 2), blk, 0, stream>>>(tm, tb, tb2, ob, ob2, om);  // offsets P->ob, Q->ob2 (om untouched)
    k5s<<<HBLOCKS, blk, 0, stream>>>(vpb, vpb2, vpm, ob, ob2, om, I, B, partL);
    k6_out<<<1, 1024, 0, stream>>>(partL, (float*)d_out);
}